// Round 9
// baseline (5766.113 us; speedup 1.0000x reference)
//
#include <hip/hip_runtime.h>

#define N_NODES 50000
#define N_GRAPHS 500
#define E_SPARSE 800000
#define E_DENSE 3200000
#define IN_DIM 128
#define HID 128
#define OUT_D 64
#define N_LAYERS 3
#define NEG_SLOPE 0.2f

#define BUCKET_SHIFT 7                 // 128 dst nodes per bucket
#define BUCKET_N 128
#define NBUCK 391                      // ceil(50000/128)
#define NC 13                          // src-coarse slices (4096 nodes = 1MB of h)
#define SRC_SHIFT 12
#define NKB (NBUCK * NC)               // 5083 composite buckets
#define NTD2 384                       // dense edge tiles
#define NTS2 128                       // sparse edge tiles
#define TSD2 8334                      // ceil(E_DENSE/NTD2)
#define TSS2 6250                      // E_SPARSE/NTS2
#define MD2 (NKB * NTD2)               // 1,951,872
#define MATN2 (MD2 + NKB * NTS2)       // 2,602,496
#define NT 32                          // nodes per node_mm block
typedef unsigned int u32;

// ---------------- edge sort by (dst_bucket, src_coarse); no global atomics --

// key: kb = (dst>>7)*NC + (src>>12). Per-tile LDS histogram -> mat.
__global__ __launch_bounds__(256) void tile_count_all(
    const int* __restrict__ srcD, const int* __restrict__ dstD,
    const int* __restrict__ srcS, const int* __restrict__ dstS,
    int* __restrict__ mat) {
    __shared__ int hc[NKB];
    int t = threadIdx.x, tile = blockIdx.x;
    for (int i = t; i < NKB; i += 256) hc[i] = 0;
    __syncthreads();
    if (tile < NTD2) {
        int beg = tile * TSD2, end = min(E_DENSE, beg + TSD2);
        for (int i = beg + t; i < end; i += 256) {
            int kb = (dstD[i] >> BUCKET_SHIFT) * NC + (srcD[i] >> SRC_SHIFT);
            atomicAdd(&hc[kb], 1);
        }
        __syncthreads();
        for (int i = t; i < NKB; i += 256) mat[i * NTD2 + tile] = hc[i];
    } else {
        int st = tile - NTD2;
        int beg = st * TSS2, end = min(E_SPARSE, beg + TSS2);
        for (int i = beg + t; i < end; i += 256) {
            int kb = (dstS[i] >> BUCKET_SHIFT) * NC + (srcS[i] >> SRC_SHIFT);
            atomicAdd(&hc[kb], 1);
        }
        __syncthreads();
        for (int i = t; i < NKB; i += 256) mat[MD2 + i * NTS2 + st] = hc[i];
    }
}

// scan level-0: 512 threads, 4 elems/thread => 2048/block
__global__ void scan_lvl0(const int* __restrict__ cnt, int n,
                          int* __restrict__ out, int* __restrict__ bsum) {
    __shared__ int sm[512];
    int t = threadIdx.x;
    int base = blockIdx.x * 2048 + t * 4;
    int v0 = (base + 0 < n) ? cnt[base + 0] : 0;
    int v1 = (base + 1 < n) ? cnt[base + 1] : 0;
    int v2 = (base + 2 < n) ? cnt[base + 2] : 0;
    int v3 = (base + 3 < n) ? cnt[base + 3] : 0;
    int s = v0 + v1 + v2 + v3;
    sm[t] = s;
    __syncthreads();
    for (int off = 1; off < 512; off <<= 1) {
        int a = (t >= off) ? sm[t - off] : 0;
        __syncthreads();
        sm[t] += a;
        __syncthreads();
    }
    int excl = sm[t] - s;
    if (base + 0 < n) out[base + 0] = excl;
    if (base + 1 < n) out[base + 1] = excl + v0;
    if (base + 2 < n) out[base + 2] = excl + v0 + v1;
    if (base + 3 < n) out[base + 3] = excl + v0 + v1 + v2;
    if (t == 511) bsum[blockIdx.x] = sm[511];
}

// level-1: single block, 512 threads x 4 => up to 2048 block sums
__global__ void scan_lvl1b(const int* __restrict__ bsum, int nb,
                           int* __restrict__ bsumx) {
    __shared__ int sm[512];
    int t = threadIdx.x;
    int base = t * 4;
    int v0 = (base + 0 < nb) ? bsum[base + 0] : 0;
    int v1 = (base + 1 < nb) ? bsum[base + 1] : 0;
    int v2 = (base + 2 < nb) ? bsum[base + 2] : 0;
    int v3 = (base + 3 < nb) ? bsum[base + 3] : 0;
    int s = v0 + v1 + v2 + v3;
    sm[t] = s;
    __syncthreads();
    for (int off = 1; off < 512; off <<= 1) {
        int a = (t >= off) ? sm[t - off] : 0;
        __syncthreads();
        sm[t] += a;
        __syncthreads();
    }
    int excl = sm[t] - s;
    if (base + 0 < nb) bsumx[base + 0] = excl;
    if (base + 1 < nb) bsumx[base + 1] = excl + v0;
    if (base + 2 < nb) bsumx[base + 2] = excl + v0 + v1;
    if (base + 3 < nb) bsumx[base + 3] = excl + v0 + v1 + v2;
}

__global__ void scan_add(int* __restrict__ out, int n, const int* __restrict__ bsumx,
                         int Etot) {
    int i = blockIdx.x * blockDim.x + threadIdx.x;
    if (i < n) out[i] += bsumx[i >> 11];
    if (i == 0) out[n] = Etot;
}

// scatter packed (dst_low7<<16 | src) into exclusively-owned (kb,tile) runs
__global__ __launch_bounds__(256) void tile_scatter_all(
    const int* __restrict__ srcD, const int* __restrict__ dstD,
    const int* __restrict__ srcS, const int* __restrict__ dstS,
    const int* __restrict__ matx, u32* __restrict__ pairs) {
    __shared__ int cur[NKB];
    int t = threadIdx.x, tile = blockIdx.x;
    const int* src;
    const int* dst;
    int beg, end;
    if (tile < NTD2) {
        for (int i = t; i < NKB; i += 256) cur[i] = matx[i * NTD2 + tile];
        src = srcD; dst = dstD;
        beg = tile * TSD2; end = min(E_DENSE, beg + TSD2);
    } else {
        int st = tile - NTD2;
        for (int i = t; i < NKB; i += 256) cur[i] = matx[MD2 + i * NTS2 + st];
        src = srcS; dst = dstS;
        beg = st * TSS2; end = min(E_SPARSE, beg + TSS2);
    }
    __syncthreads();
    for (int i = beg + t; i < end; i += 256) {
        int d = dst[i];
        int s = src[i];
        int kb = (d >> BUCKET_SHIFT) * NC + (s >> SRC_SHIFT);
        int pos = atomicAdd(&cur[kb], 1);
        pairs[pos] = (u32)s | ((u32)(d & (BUCKET_N - 1)) << 16);
    }
}

// ---------------- per-layer kernels ----------------------------------------

// 256 threads, 32 nodes/block. W (32KB) + X tile (16.9KB, padded) in LDS.
__global__ __launch_bounds__(256) void node_mm2(
    const float* __restrict__ x, const float* __restrict__ W,
    const float* __restrict__ a_s, const float* __restrict__ a_d,
    float* __restrict__ h, float* __restrict__ s_src, float* __restrict__ s_dst) {
    __shared__ float Wl[IN_DIM * OUT_D];
    __shared__ float4 Xl4[NT * 33];
    int t = threadIdx.x;
    int nbase = blockIdx.x * NT;

    const float4* W4 = (const float4*)W;
    float4* Wl4 = (float4*)Wl;
#pragma unroll
    for (int i = 0; i < 8; ++i) Wl4[t + 256 * i] = W4[t + 256 * i];

    int nrows = min(NT, N_NODES - nbase);
    const float4* X4 = (const float4*)(x + (size_t)nbase * IN_DIM);
    for (int i = t; i < nrows * 32; i += 256)
        Xl4[(i >> 5) * 33 + (i & 31)] = X4[i];
    __syncthreads();

    int wv = t >> 6, l = t & 63;
    int c4 = l & 15;
    int np = l >> 4;
    int n0 = wv * 8 + np * 2, n1 = n0 + 1;
    const float* Xl = (const float*)Xl4;
    const float4* Wr = (const float4*)Wl;

    float4 A0 = make_float4(0.f, 0.f, 0.f, 0.f);
    float4 A1 = make_float4(0.f, 0.f, 0.f, 0.f);
#pragma unroll 4
    for (int k = 0; k < IN_DIM; ++k) {
        float4 w4 = Wr[k * 16 + c4];
        float x0 = Xl[n0 * 132 + k];
        float x1 = Xl[n1 * 132 + k];
        A0.x += x0 * w4.x; A0.y += x0 * w4.y; A0.z += x0 * w4.z; A0.w += x0 * w4.w;
        A1.x += x1 * w4.x; A1.y += x1 * w4.y; A1.z += x1 * w4.z; A1.w += x1 * w4.w;
    }
    int gn0 = nbase + n0, gn1 = nbase + n1;
    if (gn0 < N_NODES) ((float4*)(h + (size_t)gn0 * OUT_D))[c4] = A0;
    if (gn1 < N_NODES) ((float4*)(h + (size_t)gn1 * OUT_D))[c4] = A1;

    float4 as4 = ((const float4*)a_s)[c4];
    float4 ad4 = ((const float4*)a_d)[c4];
    float ps0 = A0.x * as4.x + A0.y * as4.y + A0.z * as4.z + A0.w * as4.w;
    float pd0 = A0.x * ad4.x + A0.y * ad4.y + A0.z * ad4.z + A0.w * ad4.w;
    float ps1 = A1.x * as4.x + A1.y * as4.y + A1.z * as4.z + A1.w * as4.w;
    float pd1 = A1.x * ad4.x + A1.y * ad4.y + A1.z * ad4.z + A1.w * ad4.w;
#pragma unroll
    for (int off = 1; off < 16; off <<= 1) {
        ps0 += __shfl_xor(ps0, off); pd0 += __shfl_xor(pd0, off);
        ps1 += __shfl_xor(ps1, off); pd1 += __shfl_xor(pd1, off);
    }
    if (c4 == 0) {
        if (gn0 < N_NODES) { s_src[gn0] = ps0; s_dst[gn0] = pd0; }
        if (gn1 < N_NODES) { s_src[gn1] = ps1; s_dst[gn1] = pd1; }
    }
}

// Tiled GAT aggregation: one block per (branch, dst-bucket). 128 dst-row
// accumulators in LDS; edges streamed in ascending src_coarse so all
// co-resident blocks sweep the same ~1MB h slices together (L2-resident).
// Per edge: 64-lane coalesced h row load + conflict-free LDS f32 atomicAdd.
__global__ __launch_bounds__(256) void gat_tiled(
    const u32* __restrict__ pairs, const int* __restrict__ matx,
    const float* __restrict__ s_src, const float* __restrict__ s_dst,
    const float* __restrict__ h, const float* __restrict__ bias,
    float* __restrict__ xnext) {
    int bid = blockIdx.x;
    bool dense = bid < NBUCK;
    int b = dense ? bid : bid - NBUCK;
    int beg, end, coloff;
    if (dense) {
        beg = matx[b * NC * NTD2];
        end = matx[(b + 1) * NC * NTD2];   // b=390 -> matx[MD2] = E_DENSE
        coloff = OUT_D;
    } else {
        beg = matx[MD2 + b * NC * NTS2];
        end = matx[MD2 + (b + 1) * NC * NTS2];  // last -> matx[MATN2] = Etot
        coloff = 0;
    }

    __shared__ float acc[BUCKET_N * OUT_D];   // 32 KB
    __shared__ float zl[BUCKET_N];
    __shared__ float sdl[BUCKET_N];
    int t = threadIdx.x;
    for (int i = t; i < BUCKET_N * OUT_D; i += 256) acc[i] = 0.f;
    if (t < BUCKET_N) {
        zl[t] = 0.f;
        int n = (b << BUCKET_SHIFT) + t;
        sdl[t] = (n < N_NODES) ? s_dst[n] : 0.f;
    }
    __syncthreads();

    int wv = t >> 6, lane = t & 63;
    for (int cb = beg + wv * 64; cb < end; cb += 256) {
        int e = cb + lane;
        u32 pr = 0;
        float pv = 0.f;
        if (e < end) {
            pr = pairs[e];
            int src = pr & 0xffffu;
            int dstl = (pr >> 16) & (BUCKET_N - 1);
            float sc = s_src[src] + sdl[dstl];
            sc = (sc >= 0.f) ? sc : NEG_SLOPE * sc;
            pv = __expf(sc);
            atomicAdd(&zl[dstl], pv);
        }
        int nvalid = min(64, end - cb);
        if (nvalid == 64) {
#pragma unroll
            for (int j = 0; j < 64; ++j) {
                u32 prj = (u32)__shfl((int)pr, j);
                float pj = __shfl(pv, j);
                int srcj = prj & 0xffffu;
                int dstlj = (prj >> 16) & (BUCKET_N - 1);
                float hv = h[srcj * OUT_D + lane];
                atomicAdd(&acc[dstlj * OUT_D + lane], pj * hv);
            }
        } else {
            for (int j = 0; j < nvalid; ++j) {
                u32 prj = (u32)__shfl((int)pr, j);
                float pj = __shfl(pv, j);
                int srcj = prj & 0xffffu;
                int dstlj = (prj >> 16) & (BUCKET_N - 1);
                float hv = h[srcj * OUT_D + lane];
                atomicAdd(&acc[dstlj * OUT_D + lane], pj * hv);
            }
        }
    }
    __syncthreads();

    // finalize: self-loop + normalize + bias + relu + write
    float bv = bias[lane];
    for (int i = 0; i < BUCKET_N / 4; ++i) {
        int nl = wv * (BUCKET_N / 4) + i;
        int n = (b << BUCKET_SHIFT) + nl;
        if (n >= N_NODES) break;
        float e0 = s_src[n] + sdl[nl];
        e0 = (e0 >= 0.f) ? e0 : NEG_SLOPE * e0;
        float p0 = __expf(e0);
        float hv = h[n * OUT_D + lane];
        float o = (acc[nl * OUT_D + lane] + p0 * hv) / (zl[nl] + p0) + bv;
        xnext[(size_t)n * HID + coloff + lane] = fmaxf(o, 0.f);
    }
}

// Fused global_add_pool + final linear: one block per graph (batch is sorted).
__global__ __launch_bounds__(128) void pool_final(
    const float* __restrict__ x, const int* __restrict__ batch,
    const float* __restrict__ fw, const float* __restrict__ fb,
    float* __restrict__ y) {
    int b = blockIdx.x;
    int t = threadIdx.x;
    __shared__ int sbeg, send;
    if (t == 0) {
        int lo = 0, hi = N_NODES;
        while (lo < hi) { int mid = (lo + hi) >> 1; if (batch[mid] < b) lo = mid + 1; else hi = mid; }
        sbeg = lo;
        hi = N_NODES;
        while (lo < hi) { int mid = (lo + hi) >> 1; if (batch[mid] < b + 1) lo = mid + 1; else hi = mid; }
        send = lo;
    }
    __syncthreads();
    float acc = 0.f;
    for (int n = sbeg; n < send; ++n) acc += x[(size_t)n * HID + t];
    __shared__ float sm[HID];
    sm[t] = acc * fw[t];
    __syncthreads();
    for (int off = 64; off > 0; off >>= 1) {
        if (t < off) sm[t] += sm[t + off];
        __syncthreads();
    }
    if (t == 0) y[b] = sm[0] + fb[0];
}

extern "C" void kernel_launch(void* const* d_in, const int* in_sizes, int n_in,
                              void* d_out, int out_size, void* d_ws, size_t ws_size,
                              hipStream_t stream) {
    const float* x_in    = (const float*)d_in[0];
    const int*   ei      = (const int*)d_in[1];
    const int*   di      = (const int*)d_in[2];
    const int*   batch   = (const int*)d_in[3];
    const float* lin_w   = (const float*)d_in[4];
    const float* att_src = (const float*)d_in[5];
    const float* att_dst = (const float*)d_in[6];
    const float* bias    = (const float*)d_in[7];
    const float* fw      = (const float*)d_in[8];
    const float* fb      = (const float*)d_in[9];
    float* y = (float*)d_out;

    char* wsb = (char*)d_ws;
    size_t off = 0;
    auto alloc_b = [&](size_t bytes) { void* p = (void*)(wsb + off);
                                       off += (bytes + 15) & ~(size_t)15; return p; };

    float* xbuf0 = (float*)alloc_b((size_t)N_NODES * HID * 4);
    float* xbuf1 = (float*)alloc_b((size_t)N_NODES * HID * 4);
    float* h     = (float*)alloc_b((size_t)N_NODES * OUT_D * 4);
    float* s_src = (float*)alloc_b(N_NODES * 4);
    float* s_dst = (float*)alloc_b(N_NODES * 4);
    // sortbuf: mat (10.4MB) during count/scan, then pairs (16MB) after scan
    void* sortbuf = alloc_b((size_t)(E_DENSE + E_SPARSE) * 4);
    int* mat   = (int*)sortbuf;
    u32* pairs = (u32*)sortbuf;
    int* matx  = (int*)alloc_b(((size_t)MATN2 + 1) * 4);
    int* bsum  = (int*)alloc_b(2048 * 4);
    int* bsumx = (int*)alloc_b(2048 * 4);

    const int* srcD = di;
    const int* dstD = di + E_DENSE;
    const int* srcS = ei;
    const int* dstS = ei + E_SPARSE;

    const int SCAN_BLKS = (MATN2 + 2047) / 2048;  // 1271 <= 2048

    // ---- edge sort build (4 passes + tiny scans, shared across layers) ----
    tile_count_all<<<NTD2 + NTS2, 256, 0, stream>>>(srcD, dstD, srcS, dstS, mat);
    scan_lvl0<<<SCAN_BLKS, 512, 0, stream>>>(mat, MATN2, matx, bsum);
    scan_lvl1b<<<1, 512, 0, stream>>>(bsum, SCAN_BLKS, bsumx);
    scan_add<<<(MATN2 + 256) / 256, 256, 0, stream>>>(matx, MATN2, bsumx,
                                                      E_DENSE + E_SPARSE);
    tile_scatter_all<<<NTD2 + NTS2, 256, 0, stream>>>(srcD, dstD, srcS, dstS,
                                                      matx, pairs);

    // layer 0 reads x_in directly; outputs ping-pong xbuf1 -> xbuf0 -> xbuf1
    const float* cur = x_in;
    float* bufs[3] = {xbuf1, xbuf0, xbuf1};
    const int mm_grid = (N_NODES + NT - 1) / NT;
    for (int l = 0; l < N_LAYERS; ++l) {
        node_mm2<<<mm_grid, 256, 0, stream>>>(cur, lin_w + (size_t)l * HID * OUT_D,
                                              att_src + l * OUT_D, att_dst + l * OUT_D,
                                              h, s_src, s_dst);
        float* xn = bufs[l];
        gat_tiled<<<2 * NBUCK, 256, 0, stream>>>(pairs, matx, s_src, s_dst, h,
                                                 bias + l * OUT_D, xn);
        cur = xn;
    }

    pool_final<<<N_GRAPHS, 128, 0, stream>>>(cur, batch, fw, fb, y);
}

// Round 10
// 5544.757 us; speedup vs baseline: 1.0399x; 1.0399x over previous
//
#include <hip/hip_runtime.h>

#define N_NODES 50000
#define N_GRAPHS 500
#define E_SPARSE 800000
#define E_DENSE 3200000
#define IN_DIM 128
#define HID 128
#define OUT_D 64
#define N_LAYERS 3
#define NEG_SLOPE 0.2f

#define BUCKET_SHIFT 7                 // 128 dst nodes per bucket
#define BUCKET_N 128
#define NBUCK 391                      // ceil(50000/128)
#define NC 13                          // src-coarse slices (4096 nodes = 1MB of h)
#define SRC_SHIFT 12
#define NKB (NBUCK * NC)               // 5083 composite buckets
#define NTD2 384                       // dense edge tiles
#define NTS2 128                       // sparse edge tiles
#define TSD2 8334                      // ceil(E_DENSE/NTD2)
#define TSS2 6250                      // E_SPARSE/NTS2
#define MD2 (NKB * NTD2)               // 1,951,872
#define MATN2 (MD2 + NKB * NTS2)       // 2,602,496
#define NT 32                          // nodes per node_mm block
typedef unsigned int u32;

// ---------------- edge sort by (dst_bucket, src_coarse); no global atomics --

__global__ __launch_bounds__(256) void tile_count_all(
    const int* __restrict__ srcD, const int* __restrict__ dstD,
    const int* __restrict__ srcS, const int* __restrict__ dstS,
    int* __restrict__ mat) {
    __shared__ int hc[NKB];
    int t = threadIdx.x, tile = blockIdx.x;
    for (int i = t; i < NKB; i += 256) hc[i] = 0;
    __syncthreads();
    if (tile < NTD2) {
        int beg = tile * TSD2, end = min(E_DENSE, beg + TSD2);
        for (int i = beg + t; i < end; i += 256) {
            int kb = (dstD[i] >> BUCKET_SHIFT) * NC + (srcD[i] >> SRC_SHIFT);
            atomicAdd(&hc[kb], 1);
        }
        __syncthreads();
        for (int i = t; i < NKB; i += 256) mat[i * NTD2 + tile] = hc[i];
    } else {
        int st = tile - NTD2;
        int beg = st * TSS2, end = min(E_SPARSE, beg + TSS2);
        for (int i = beg + t; i < end; i += 256) {
            int kb = (dstS[i] >> BUCKET_SHIFT) * NC + (srcS[i] >> SRC_SHIFT);
            atomicAdd(&hc[kb], 1);
        }
        __syncthreads();
        for (int i = t; i < NKB; i += 256) mat[MD2 + i * NTS2 + st] = hc[i];
    }
}

__global__ void scan_lvl0(const int* __restrict__ cnt, int n,
                          int* __restrict__ out, int* __restrict__ bsum) {
    __shared__ int sm[512];
    int t = threadIdx.x;
    int base = blockIdx.x * 2048 + t * 4;
    int v0 = (base + 0 < n) ? cnt[base + 0] : 0;
    int v1 = (base + 1 < n) ? cnt[base + 1] : 0;
    int v2 = (base + 2 < n) ? cnt[base + 2] : 0;
    int v3 = (base + 3 < n) ? cnt[base + 3] : 0;
    int s = v0 + v1 + v2 + v3;
    sm[t] = s;
    __syncthreads();
    for (int off = 1; off < 512; off <<= 1) {
        int a = (t >= off) ? sm[t - off] : 0;
        __syncthreads();
        sm[t] += a;
        __syncthreads();
    }
    int excl = sm[t] - s;
    if (base + 0 < n) out[base + 0] = excl;
    if (base + 1 < n) out[base + 1] = excl + v0;
    if (base + 2 < n) out[base + 2] = excl + v0 + v1;
    if (base + 3 < n) out[base + 3] = excl + v0 + v1 + v2;
    if (t == 511) bsum[blockIdx.x] = sm[511];
}

__global__ void scan_lvl1b(const int* __restrict__ bsum, int nb,
                           int* __restrict__ bsumx) {
    __shared__ int sm[512];
    int t = threadIdx.x;
    int base = t * 4;
    int v0 = (base + 0 < nb) ? bsum[base + 0] : 0;
    int v1 = (base + 1 < nb) ? bsum[base + 1] : 0;
    int v2 = (base + 2 < nb) ? bsum[base + 2] : 0;
    int v3 = (base + 3 < nb) ? bsum[base + 3] : 0;
    int s = v0 + v1 + v2 + v3;
    sm[t] = s;
    __syncthreads();
    for (int off = 1; off < 512; off <<= 1) {
        int a = (t >= off) ? sm[t - off] : 0;
        __syncthreads();
        sm[t] += a;
        __syncthreads();
    }
    int excl = sm[t] - s;
    if (base + 0 < nb) bsumx[base + 0] = excl;
    if (base + 1 < nb) bsumx[base + 1] = excl + v0;
    if (base + 2 < nb) bsumx[base + 2] = excl + v0 + v1;
    if (base + 3 < nb) bsumx[base + 3] = excl + v0 + v1 + v2;
}

__global__ void scan_add(int* __restrict__ out, int n, const int* __restrict__ bsumx,
                         int Etot) {
    int i = blockIdx.x * blockDim.x + threadIdx.x;
    if (i < n) out[i] += bsumx[i >> 11];
    if (i == 0) out[n] = Etot;
}

__global__ __launch_bounds__(256) void tile_scatter_all(
    const int* __restrict__ srcD, const int* __restrict__ dstD,
    const int* __restrict__ srcS, const int* __restrict__ dstS,
    const int* __restrict__ matx, u32* __restrict__ pairs) {
    __shared__ int cur[NKB];
    int t = threadIdx.x, tile = blockIdx.x;
    const int* src;
    const int* dst;
    int beg, end;
    if (tile < NTD2) {
        for (int i = t; i < NKB; i += 256) cur[i] = matx[i * NTD2 + tile];
        src = srcD; dst = dstD;
        beg = tile * TSD2; end = min(E_DENSE, beg + TSD2);
    } else {
        int st = tile - NTD2;
        for (int i = t; i < NKB; i += 256) cur[i] = matx[MD2 + i * NTS2 + st];
        src = srcS; dst = dstS;
        beg = st * TSS2; end = min(E_SPARSE, beg + TSS2);
    }
    __syncthreads();
    for (int i = beg + t; i < end; i += 256) {
        int d = dst[i];
        int s = src[i];
        int kb = (d >> BUCKET_SHIFT) * NC + (s >> SRC_SHIFT);
        int pos = atomicAdd(&cur[kb], 1);
        pairs[pos] = (u32)s | ((u32)(d & (BUCKET_N - 1)) << 16);
    }
}

// ---------------- per-layer kernels ----------------------------------------

__global__ __launch_bounds__(256) void node_mm2(
    const float* __restrict__ x, const float* __restrict__ W,
    const float* __restrict__ a_s, const float* __restrict__ a_d,
    float* __restrict__ h, float* __restrict__ s_src, float* __restrict__ s_dst) {
    __shared__ float Wl[IN_DIM * OUT_D];
    __shared__ float4 Xl4[NT * 33];
    int t = threadIdx.x;
    int nbase = blockIdx.x * NT;

    const float4* W4 = (const float4*)W;
    float4* Wl4 = (float4*)Wl;
#pragma unroll
    for (int i = 0; i < 8; ++i) Wl4[t + 256 * i] = W4[t + 256 * i];

    int nrows = min(NT, N_NODES - nbase);
    const float4* X4 = (const float4*)(x + (size_t)nbase * IN_DIM);
    for (int i = t; i < nrows * 32; i += 256)
        Xl4[(i >> 5) * 33 + (i & 31)] = X4[i];
    __syncthreads();

    int wv = t >> 6, l = t & 63;
    int c4 = l & 15;
    int np = l >> 4;
    int n0 = wv * 8 + np * 2, n1 = n0 + 1;
    const float* Xl = (const float*)Xl4;
    const float4* Wr = (const float4*)Wl;

    float4 A0 = make_float4(0.f, 0.f, 0.f, 0.f);
    float4 A1 = make_float4(0.f, 0.f, 0.f, 0.f);
#pragma unroll 4
    for (int k = 0; k < IN_DIM; ++k) {
        float4 w4 = Wr[k * 16 + c4];
        float x0 = Xl[n0 * 132 + k];
        float x1 = Xl[n1 * 132 + k];
        A0.x += x0 * w4.x; A0.y += x0 * w4.y; A0.z += x0 * w4.z; A0.w += x0 * w4.w;
        A1.x += x1 * w4.x; A1.y += x1 * w4.y; A1.z += x1 * w4.z; A1.w += x1 * w4.w;
    }
    int gn0 = nbase + n0, gn1 = nbase + n1;
    if (gn0 < N_NODES) ((float4*)(h + (size_t)gn0 * OUT_D))[c4] = A0;
    if (gn1 < N_NODES) ((float4*)(h + (size_t)gn1 * OUT_D))[c4] = A1;

    float4 as4 = ((const float4*)a_s)[c4];
    float4 ad4 = ((const float4*)a_d)[c4];
    float ps0 = A0.x * as4.x + A0.y * as4.y + A0.z * as4.z + A0.w * as4.w;
    float pd0 = A0.x * ad4.x + A0.y * ad4.y + A0.z * ad4.z + A0.w * ad4.w;
    float ps1 = A1.x * as4.x + A1.y * as4.y + A1.z * as4.z + A1.w * as4.w;
    float pd1 = A1.x * ad4.x + A1.y * ad4.y + A1.z * ad4.z + A1.w * ad4.w;
#pragma unroll
    for (int off = 1; off < 16; off <<= 1) {
        ps0 += __shfl_xor(ps0, off); pd0 += __shfl_xor(pd0, off);
        ps1 += __shfl_xor(ps1, off); pd1 += __shfl_xor(pd1, off);
    }
    if (c4 == 0) {
        if (gn0 < N_NODES) { s_src[gn0] = ps0; s_dst[gn0] = pd0; }
        if (gn1 < N_NODES) { s_src[gn1] = ps1; s_dst[gn1] = pd1; }
    }
}

// Tiled GAT aggregation, restructured: one EDGE per wave-iteration slot,
// 8 slots unrolled (8 independent uniform-load -> score -> h-load -> ds_add
// chains in flight per wave). lane = output dim; acc bank = lane mod 32
// (2 lanes/bank = free). z atomics batched under one lane==0 predicate.
__global__ __launch_bounds__(256) void gat_tiled(
    const u32* __restrict__ pairs, const int* __restrict__ matx,
    const float* __restrict__ s_src, const float* __restrict__ s_dst,
    const float* __restrict__ h, const float* __restrict__ bias,
    float* __restrict__ xnext) {
    int bid = blockIdx.x;
    bool dense = bid < NBUCK;
    int b = dense ? bid : bid - NBUCK;
    int beg, end, coloff;
    if (dense) {
        beg = matx[b * NC * NTD2];
        end = matx[(b + 1) * NC * NTD2];
        coloff = OUT_D;
    } else {
        beg = matx[MD2 + b * NC * NTS2];
        end = matx[MD2 + (b + 1) * NC * NTS2];
        coloff = 0;
    }

    __shared__ float acc[BUCKET_N * OUT_D];   // 32 KB
    __shared__ float zl[BUCKET_N];
    __shared__ float sdl[BUCKET_N];
    int t = threadIdx.x;
    for (int i = t; i < BUCKET_N * OUT_D; i += 256) acc[i] = 0.f;
    if (t < BUCKET_N) {
        zl[t] = 0.f;
        int n = (b << BUCKET_SHIFT) + t;
        sdl[t] = (n < N_NODES) ? s_dst[n] : 0.f;
    }
    __syncthreads();

    int wv = t >> 6, lane = t & 63;
    int e0 = beg + wv * 8;
    for (; e0 + 8 <= end; e0 += 32) {
        u32 pr[8];
#pragma unroll
        for (int i = 0; i < 8; ++i) pr[i] = pairs[e0 + i];
        int src[8], dl[8];
        float p[8];
#pragma unroll
        for (int i = 0; i < 8; ++i) {
            src[i] = pr[i] & 0xffffu;
            dl[i] = (pr[i] >> 16) & (BUCKET_N - 1);
            float sc = s_src[src[i]] + sdl[dl[i]];
            sc = (sc >= 0.f) ? sc : NEG_SLOPE * sc;
            p[i] = __expf(sc);
        }
        float hv[8];
#pragma unroll
        for (int i = 0; i < 8; ++i) hv[i] = h[src[i] * OUT_D + lane];
#pragma unroll
        for (int i = 0; i < 8; ++i)
            atomicAdd(&acc[dl[i] * OUT_D + lane], p[i] * hv[i]);
        if (lane == 0) {
#pragma unroll
            for (int i = 0; i < 8; ++i) atomicAdd(&zl[dl[i]], p[i]);
        }
    }
    // tail: this wave's remaining (< 8) edges
    for (int e = e0; e < end && e < e0 + 8; ++e) {
        u32 pr = pairs[e];
        int src = pr & 0xffffu;
        int dl = (pr >> 16) & (BUCKET_N - 1);
        float sc = s_src[src] + sdl[dl];
        sc = (sc >= 0.f) ? sc : NEG_SLOPE * sc;
        float p = __expf(sc);
        float hv = h[src * OUT_D + lane];
        atomicAdd(&acc[dl * OUT_D + lane], p * hv);
        if (lane == 0) atomicAdd(&zl[dl], p);
    }
    __syncthreads();

    // finalize: self-loop + normalize + bias + relu + write
    float bv = bias[lane];
    for (int i = 0; i < BUCKET_N / 4; ++i) {
        int nl = wv * (BUCKET_N / 4) + i;
        int n = (b << BUCKET_SHIFT) + nl;
        if (n >= N_NODES) break;
        float e0s = s_src[n] + sdl[nl];
        e0s = (e0s >= 0.f) ? e0s : NEG_SLOPE * e0s;
        float p0 = __expf(e0s);
        float hv = h[n * OUT_D + lane];
        float o = (acc[nl * OUT_D + lane] + p0 * hv) / (zl[nl] + p0) + bv;
        xnext[(size_t)n * HID + coloff + lane] = fmaxf(o, 0.f);
    }
}

// Fused global_add_pool + final linear: one block per graph (batch is sorted).
__global__ __launch_bounds__(128) void pool_final(
    const float* __restrict__ x, const int* __restrict__ batch,
    const float* __restrict__ fw, const float* __restrict__ fb,
    float* __restrict__ y) {
    int b = blockIdx.x;
    int t = threadIdx.x;
    __shared__ int sbeg, send;
    if (t == 0) {
        int lo = 0, hi = N_NODES;
        while (lo < hi) { int mid = (lo + hi) >> 1; if (batch[mid] < b) lo = mid + 1; else hi = mid; }
        sbeg = lo;
        hi = N_NODES;
        while (lo < hi) { int mid = (lo + hi) >> 1; if (batch[mid] < b + 1) lo = mid + 1; else hi = mid; }
        send = lo;
    }
    __syncthreads();
    float acc = 0.f;
    for (int n = sbeg; n < send; ++n) acc += x[(size_t)n * HID + t];
    __shared__ float sm[HID];
    sm[t] = acc * fw[t];
    __syncthreads();
    for (int off = 64; off > 0; off >>= 1) {
        if (t < off) sm[t] += sm[t + off];
        __syncthreads();
    }
    if (t == 0) y[b] = sm[0] + fb[0];
}

extern "C" void kernel_launch(void* const* d_in, const int* in_sizes, int n_in,
                              void* d_out, int out_size, void* d_ws, size_t ws_size,
                              hipStream_t stream) {
    const float* x_in    = (const float*)d_in[0];
    const int*   ei      = (const int*)d_in[1];
    const int*   di      = (const int*)d_in[2];
    const int*   batch   = (const int*)d_in[3];
    const float* lin_w   = (const float*)d_in[4];
    const float* att_src = (const float*)d_in[5];
    const float* att_dst = (const float*)d_in[6];
    const float* bias    = (const float*)d_in[7];
    const float* fw      = (const float*)d_in[8];
    const float* fb      = (const float*)d_in[9];
    float* y = (float*)d_out;

    char* wsb = (char*)d_ws;
    size_t off = 0;
    auto alloc_b = [&](size_t bytes) { void* p = (void*)(wsb + off);
                                       off += (bytes + 15) & ~(size_t)15; return p; };

    float* xbuf0 = (float*)alloc_b((size_t)N_NODES * HID * 4);
    float* xbuf1 = (float*)alloc_b((size_t)N_NODES * HID * 4);
    float* h     = (float*)alloc_b((size_t)N_NODES * OUT_D * 4);
    float* s_src = (float*)alloc_b(N_NODES * 4);
    float* s_dst = (float*)alloc_b(N_NODES * 4);
    void* sortbuf = alloc_b((size_t)(E_DENSE + E_SPARSE) * 4);
    int* mat   = (int*)sortbuf;
    u32* pairs = (u32*)sortbuf;
    int* matx  = (int*)alloc_b(((size_t)MATN2 + 1) * 4);
    int* bsum  = (int*)alloc_b(2048 * 4);
    int* bsumx = (int*)alloc_b(2048 * 4);

    const int* srcD = di;
    const int* dstD = di + E_DENSE;
    const int* srcS = ei;
    const int* dstS = ei + E_SPARSE;

    const int SCAN_BLKS = (MATN2 + 2047) / 2048;  // 1271

    tile_count_all<<<NTD2 + NTS2, 256, 0, stream>>>(srcD, dstD, srcS, dstS, mat);
    scan_lvl0<<<SCAN_BLKS, 512, 0, stream>>>(mat, MATN2, matx, bsum);
    scan_lvl1b<<<1, 512, 0, stream>>>(bsum, SCAN_BLKS, bsumx);
    scan_add<<<(MATN2 + 256) / 256, 256, 0, stream>>>(matx, MATN2, bsumx,
                                                      E_DENSE + E_SPARSE);
    tile_scatter_all<<<NTD2 + NTS2, 256, 0, stream>>>(srcD, dstD, srcS, dstS,
                                                      matx, pairs);

    const float* cur = x_in;
    float* bufs[3] = {xbuf1, xbuf0, xbuf1};
    const int mm_grid = (N_NODES + NT - 1) / NT;
    for (int l = 0; l < N_LAYERS; ++l) {
        node_mm2<<<mm_grid, 256, 0, stream>>>(cur, lin_w + (size_t)l * HID * OUT_D,
                                              att_src + l * OUT_D, att_dst + l * OUT_D,
                                              h, s_src, s_dst);
        float* xn = bufs[l];
        gat_tiled<<<2 * NBUCK, 256, 0, stream>>>(pairs, matx, s_src, s_dst, h,
                                                 bias + l * OUT_D, xn);
        cur = xn;
    }

    pool_final<<<N_GRAPHS, 128, 0, stream>>>(cur, batch, fw, fb, y);
}

// Round 11
// 691.128 us; speedup vs baseline: 8.3431x; 8.0228x over previous
//
#include <hip/hip_runtime.h>

#define N_NODES 50000
#define N_GRAPHS 500
#define E_SPARSE 800000
#define E_DENSE 3200000
#define IN_DIM 128
#define HID 128
#define OUT_D 64
#define N_LAYERS 3
#define NEG_SLOPE 0.2f

#define BUCKET_SHIFT 7                 // 128 dst nodes per bucket
#define BUCKET_N 128
#define NBUCK 391                      // ceil(50000/128)
#define NC 13                          // src-coarse slices (4096 nodes = 1MB of h)
#define SRC_SHIFT 12
#define NKB (NBUCK * NC)               // 5083 composite buckets
#define NTD2 384                       // dense edge tiles
#define NTS2 128                       // sparse edge tiles
#define TSD2 8334                      // ceil(E_DENSE/NTD2)
#define TSS2 6250                      // E_SPARSE/NTS2
#define MD2 (NKB * NTD2)               // 1,951,872
#define MATN2 (MD2 + NKB * NTS2)       // 2,602,496
#define NT 32                          // nodes per node_mm block
typedef unsigned int u32;
typedef unsigned short u16;

// ------- edge sort by (dst_bucket, src_coarse) then per-dst CSR ------------
// Sorted-by-slice rows => all waves sweep h slices 0..12 in step => live h
// working set ~2-4MB (L2-resident) instead of 12.8MB.

__global__ __launch_bounds__(256) void tile_count_all(
    const int* __restrict__ srcD, const int* __restrict__ dstD,
    const int* __restrict__ srcS, const int* __restrict__ dstS,
    int* __restrict__ mat) {
    __shared__ int hc[NKB];
    int t = threadIdx.x, tile = blockIdx.x;
    for (int i = t; i < NKB; i += 256) hc[i] = 0;
    __syncthreads();
    if (tile < NTD2) {
        int beg = tile * TSD2, end = min(E_DENSE, beg + TSD2);
        for (int i = beg + t; i < end; i += 256) {
            int kb = (dstD[i] >> BUCKET_SHIFT) * NC + (srcD[i] >> SRC_SHIFT);
            atomicAdd(&hc[kb], 1);
        }
        __syncthreads();
        for (int i = t; i < NKB; i += 256) mat[i * NTD2 + tile] = hc[i];
    } else {
        int st = tile - NTD2;
        int beg = st * TSS2, end = min(E_SPARSE, beg + TSS2);
        for (int i = beg + t; i < end; i += 256) {
            int kb = (dstS[i] >> BUCKET_SHIFT) * NC + (srcS[i] >> SRC_SHIFT);
            atomicAdd(&hc[kb], 1);
        }
        __syncthreads();
        for (int i = t; i < NKB; i += 256) mat[MD2 + i * NTS2 + st] = hc[i];
    }
}

__global__ void scan_lvl0(const int* __restrict__ cnt, int n,
                          int* __restrict__ out, int* __restrict__ bsum) {
    __shared__ int sm[512];
    int t = threadIdx.x;
    int base = blockIdx.x * 2048 + t * 4;
    int v0 = (base + 0 < n) ? cnt[base + 0] : 0;
    int v1 = (base + 1 < n) ? cnt[base + 1] : 0;
    int v2 = (base + 2 < n) ? cnt[base + 2] : 0;
    int v3 = (base + 3 < n) ? cnt[base + 3] : 0;
    int s = v0 + v1 + v2 + v3;
    sm[t] = s;
    __syncthreads();
    for (int off = 1; off < 512; off <<= 1) {
        int a = (t >= off) ? sm[t - off] : 0;
        __syncthreads();
        sm[t] += a;
        __syncthreads();
    }
    int excl = sm[t] - s;
    if (base + 0 < n) out[base + 0] = excl;
    if (base + 1 < n) out[base + 1] = excl + v0;
    if (base + 2 < n) out[base + 2] = excl + v0 + v1;
    if (base + 3 < n) out[base + 3] = excl + v0 + v1 + v2;
    if (t == 511) bsum[blockIdx.x] = sm[511];
}

__global__ void scan_lvl1b(const int* __restrict__ bsum, int nb,
                           int* __restrict__ bsumx) {
    __shared__ int sm[512];
    int t = threadIdx.x;
    int base = t * 4;
    int v0 = (base + 0 < nb) ? bsum[base + 0] : 0;
    int v1 = (base + 1 < nb) ? bsum[base + 1] : 0;
    int v2 = (base + 2 < nb) ? bsum[base + 2] : 0;
    int v3 = (base + 3 < nb) ? bsum[base + 3] : 0;
    int s = v0 + v1 + v2 + v3;
    sm[t] = s;
    __syncthreads();
    for (int off = 1; off < 512; off <<= 1) {
        int a = (t >= off) ? sm[t - off] : 0;
        __syncthreads();
        sm[t] += a;
        __syncthreads();
    }
    int excl = sm[t] - s;
    if (base + 0 < nb) bsumx[base + 0] = excl;
    if (base + 1 < nb) bsumx[base + 1] = excl + v0;
    if (base + 2 < nb) bsumx[base + 2] = excl + v0 + v1;
    if (base + 3 < nb) bsumx[base + 3] = excl + v0 + v1 + v2;
}

__global__ void scan_add(int* __restrict__ out, int n, const int* __restrict__ bsumx,
                         int Etot) {
    int i = blockIdx.x * blockDim.x + threadIdx.x;
    if (i < n) out[i] += bsumx[i >> 11];
    if (i == 0) out[n] = Etot;
}

__global__ __launch_bounds__(256) void tile_scatter_all(
    const int* __restrict__ srcD, const int* __restrict__ dstD,
    const int* __restrict__ srcS, const int* __restrict__ dstS,
    const int* __restrict__ matx, u32* __restrict__ pairs) {
    __shared__ int cur[NKB];
    int t = threadIdx.x, tile = blockIdx.x;
    const int* src;
    const int* dst;
    int beg, end;
    if (tile < NTD2) {
        for (int i = t; i < NKB; i += 256) cur[i] = matx[i * NTD2 + tile];
        src = srcD; dst = dstD;
        beg = tile * TSD2; end = min(E_DENSE, beg + TSD2);
    } else {
        int st = tile - NTD2;
        for (int i = t; i < NKB; i += 256) cur[i] = matx[MD2 + i * NTS2 + st];
        src = srcS; dst = dstS;
        beg = st * TSS2; end = min(E_SPARSE, beg + TSS2);
    }
    __syncthreads();
    for (int i = beg + t; i < end; i += 256) {
        int d = dst[i];
        int s = src[i];
        int kb = (d >> BUCKET_SHIFT) * NC + (s >> SRC_SHIFT);
        int pos = atomicAdd(&cur[kb], 1);
        pairs[pos] = (u32)s | ((u32)(d & (BUCKET_N - 1)) << 16);
    }
}

// per-bucket sort into per-dst CSR rows, PRESERVING slice order within each
// row (scatter one slice segment at a time, sync between slices).
__global__ __launch_bounds__(256) void bucket_to_csr_all(
    const u32* __restrict__ pairs, const int* __restrict__ matx,
    int* __restrict__ rowD, u16* __restrict__ csrcD,
    int* __restrict__ rowS, u16* __restrict__ csrcS) {
    int bid = blockIdx.x;
    int t = threadIdx.x;
    bool dense = bid < NBUCK;
    int b = dense ? bid : bid - NBUCK;
    int idx0 = dense ? (b * NC * NTD2) : (MD2 + b * NC * NTS2);
    int stride = dense ? NTD2 : NTS2;
    int base = dense ? 0 : E_DENSE;
    int* rowptr = dense ? rowD : rowS;
    u16* csrc = dense ? csrcD : csrcS;

    int beg = matx[idx0];
    int end = matx[idx0 + NC * stride];
    __shared__ int lcnt[BUCKET_N];
    __shared__ int lofs[BUCKET_N];
    if (t < BUCKET_N) lcnt[t] = 0;
    __syncthreads();
    for (int k = beg + t; k < end; k += 256)
        atomicAdd(&lcnt[(pairs[k] >> 16) & (BUCKET_N - 1)], 1);
    __syncthreads();
    if (t < BUCKET_N) lofs[t] = lcnt[t];
    __syncthreads();
    for (int off = 1; off < BUCKET_N; off <<= 1) {
        int a = (t < BUCKET_N && t >= off) ? lofs[t - off] : 0;
        __syncthreads();
        if (t < BUCKET_N) lofs[t] += a;
        __syncthreads();
    }
    int node = (b << BUCKET_SHIFT) + t;
    int lbeg = beg - base;
    if (t < BUCKET_N) {
        int excl = lofs[t] - lcnt[t];
        if (node < N_NODES) rowptr[node] = lbeg + excl;
        lcnt[t] = excl;  // reuse as cursor
    }
    if (b == NBUCK - 1 && t == 0)
        rowptr[N_NODES] = dense ? E_DENSE : E_SPARSE;
    __syncthreads();
    // slice-by-slice stable scatter
    for (int c = 0; c < NC; ++c) {
        int cb = matx[idx0 + c * stride];
        int ce = matx[idx0 + (c + 1) * stride];
        for (int k = cb + t; k < ce; k += 256) {
            u32 pr = pairs[k];
            int dl = (pr >> 16) & (BUCKET_N - 1);
            int pos = atomicAdd(&lcnt[dl], 1);
            csrc[lbeg + pos] = (u16)(pr & 0xffffu);
        }
        __syncthreads();
    }
}

// ---------------- per-layer kernels ----------------------------------------

__global__ __launch_bounds__(256) void node_mm2(
    const float* __restrict__ x, const float* __restrict__ W,
    const float* __restrict__ a_s, const float* __restrict__ a_d,
    float* __restrict__ h, float* __restrict__ s_src, float* __restrict__ s_dst) {
    __shared__ float Wl[IN_DIM * OUT_D];
    __shared__ float4 Xl4[NT * 33];
    int t = threadIdx.x;
    int nbase = blockIdx.x * NT;

    const float4* W4 = (const float4*)W;
    float4* Wl4 = (float4*)Wl;
#pragma unroll
    for (int i = 0; i < 8; ++i) Wl4[t + 256 * i] = W4[t + 256 * i];

    int nrows = min(NT, N_NODES - nbase);
    const float4* X4 = (const float4*)(x + (size_t)nbase * IN_DIM);
    for (int i = t; i < nrows * 32; i += 256)
        Xl4[(i >> 5) * 33 + (i & 31)] = X4[i];
    __syncthreads();

    int wv = t >> 6, l = t & 63;
    int c4 = l & 15;
    int np = l >> 4;
    int n0 = wv * 8 + np * 2, n1 = n0 + 1;
    const float* Xl = (const float*)Xl4;
    const float4* Wr = (const float4*)Wl;

    float4 A0 = make_float4(0.f, 0.f, 0.f, 0.f);
    float4 A1 = make_float4(0.f, 0.f, 0.f, 0.f);
#pragma unroll 4
    for (int k = 0; k < IN_DIM; ++k) {
        float4 w4 = Wr[k * 16 + c4];
        float x0 = Xl[n0 * 132 + k];
        float x1 = Xl[n1 * 132 + k];
        A0.x += x0 * w4.x; A0.y += x0 * w4.y; A0.z += x0 * w4.z; A0.w += x0 * w4.w;
        A1.x += x1 * w4.x; A1.y += x1 * w4.y; A1.z += x1 * w4.z; A1.w += x1 * w4.w;
    }
    int gn0 = nbase + n0, gn1 = nbase + n1;
    if (gn0 < N_NODES) ((float4*)(h + (size_t)gn0 * OUT_D))[c4] = A0;
    if (gn1 < N_NODES) ((float4*)(h + (size_t)gn1 * OUT_D))[c4] = A1;

    float4 as4 = ((const float4*)a_s)[c4];
    float4 ad4 = ((const float4*)a_d)[c4];
    float ps0 = A0.x * as4.x + A0.y * as4.y + A0.z * as4.z + A0.w * as4.w;
    float pd0 = A0.x * ad4.x + A0.y * ad4.y + A0.z * ad4.z + A0.w * ad4.w;
    float ps1 = A1.x * as4.x + A1.y * as4.y + A1.z * as4.z + A1.w * as4.w;
    float pd1 = A1.x * ad4.x + A1.y * ad4.y + A1.z * ad4.z + A1.w * ad4.w;
#pragma unroll
    for (int off = 1; off < 16; off <<= 1) {
        ps0 += __shfl_xor(ps0, off); pd0 += __shfl_xor(pd0, off);
        ps1 += __shfl_xor(ps1, off); pd1 += __shfl_xor(pd1, off);
    }
    if (c4 == 0) {
        if (gn0 < N_NODES) { s_src[gn0] = ps0; s_dst[gn0] = pd0; }
        if (gn1 < N_NODES) { s_src[gn1] = ps1; s_dst[gn1] = pd1; }
    }
}

// Fused GAT aggregation for both branches (R8 structure, 2x unroll, VGPR~24).
// Rows are slice-sorted => chip-wide synchronized sweep over h slices.
__global__ __launch_bounds__(256) void gat_aggr2(
    const int* __restrict__ rowS, const u16* __restrict__ csrcS,
    const int* __restrict__ rowD, const u16* __restrict__ csrcD,
    const float* __restrict__ s_src, const float* __restrict__ s_dst,
    const float* __restrict__ h, const float* __restrict__ bias,
    float* __restrict__ xnext, int ngrid) {
    int bid = blockIdx.x;
    const int* rowptr;
    const u16* csrc;
    int col_off;
    if (bid < ngrid) { rowptr = rowS; csrc = csrcS; col_off = 0; }
    else { bid -= ngrid; rowptr = rowD; csrc = csrcD; col_off = OUT_D; }

    int node = bid * 4 + (threadIdx.x >> 6);
    if (node >= N_NODES) return;
    int lane = threadIdx.x & 63;
    int grp = lane >> 3;   // 0..7
    int sub = lane & 7;    // 0..7

    int beg = rowptr[node];
    int end = rowptr[node + 1];
    float sd = s_dst[node];

    const float4* h4 = (const float4*)h;
    float4 a0 = make_float4(0.f, 0.f, 0.f, 0.f);
    float4 a1 = make_float4(0.f, 0.f, 0.f, 0.f);
    float z = 0.f;

    int k = beg + grp;
    for (; k + 8 < end; k += 16) {
        int s0 = csrc[k];
        int s1 = csrc[k + 8];
        float e0 = s_src[s0] + sd;
        float e1 = s_src[s1] + sd;
        e0 = (e0 >= 0.f) ? e0 : NEG_SLOPE * e0;
        e1 = (e1 >= 0.f) ? e1 : NEG_SLOPE * e1;
        float p0 = __expf(e0);
        float p1 = __expf(e1);
        float4 u0 = h4[(size_t)s0 * 16 + sub];
        float4 u1 = h4[(size_t)s0 * 16 + sub + 8];
        float4 v0 = h4[(size_t)s1 * 16 + sub];
        float4 v1 = h4[(size_t)s1 * 16 + sub + 8];
        z += p0 + p1;
        a0.x += p0 * u0.x + p1 * v0.x; a0.y += p0 * u0.y + p1 * v0.y;
        a0.z += p0 * u0.z + p1 * v0.z; a0.w += p0 * u0.w + p1 * v0.w;
        a1.x += p0 * u1.x + p1 * v1.x; a1.y += p0 * u1.y + p1 * v1.y;
        a1.z += p0 * u1.z + p1 * v1.z; a1.w += p0 * u1.w + p1 * v1.w;
    }
    if (k < end) {
        int s0 = csrc[k];
        float e0 = s_src[s0] + sd;
        e0 = (e0 >= 0.f) ? e0 : NEG_SLOPE * e0;
        float p0 = __expf(e0);
        float4 u0 = h4[(size_t)s0 * 16 + sub];
        float4 u1 = h4[(size_t)s0 * 16 + sub + 8];
        z += p0;
        a0.x += p0 * u0.x; a0.y += p0 * u0.y; a0.z += p0 * u0.z; a0.w += p0 * u0.w;
        a1.x += p0 * u1.x; a1.y += p0 * u1.y; a1.z += p0 * u1.z; a1.w += p0 * u1.w;
    }
    if (grp == 0) {  // self-loop exactly once
        float e0 = s_src[node] + sd;
        e0 = (e0 >= 0.f) ? e0 : NEG_SLOPE * e0;
        float p0 = __expf(e0);
        float4 u0 = h4[(size_t)node * 16 + sub];
        float4 u1 = h4[(size_t)node * 16 + sub + 8];
        z += p0;
        a0.x += p0 * u0.x; a0.y += p0 * u0.y; a0.z += p0 * u0.z; a0.w += p0 * u0.w;
        a1.x += p0 * u1.x; a1.y += p0 * u1.y; a1.z += p0 * u1.z; a1.w += p0 * u1.w;
    }
#pragma unroll
    for (int off = 8; off <= 32; off <<= 1) {
        a0.x += __shfl_xor(a0.x, off); a0.y += __shfl_xor(a0.y, off);
        a0.z += __shfl_xor(a0.z, off); a0.w += __shfl_xor(a0.w, off);
        a1.x += __shfl_xor(a1.x, off); a1.y += __shfl_xor(a1.y, off);
        a1.z += __shfl_xor(a1.z, off); a1.w += __shfl_xor(a1.w, off);
        z += __shfl_xor(z, off);
    }
    if (grp == 0) {
        float inv = 1.f / z;
        const float4* b4 = (const float4*)bias;
        float4 b0 = b4[sub], b1 = b4[sub + 8];
        float4 o0, o1;
        o0.x = a0.x * inv + b0.x; o0.y = a0.y * inv + b0.y;
        o0.z = a0.z * inv + b0.z; o0.w = a0.w * inv + b0.w;
        o1.x = a1.x * inv + b1.x; o1.y = a1.y * inv + b1.y;
        o1.z = a1.z * inv + b1.z; o1.w = a1.w * inv + b1.w;
        o0.x = fmaxf(o0.x, 0.f); o0.y = fmaxf(o0.y, 0.f);
        o0.z = fmaxf(o0.z, 0.f); o0.w = fmaxf(o0.w, 0.f);
        o1.x = fmaxf(o1.x, 0.f); o1.y = fmaxf(o1.y, 0.f);
        o1.z = fmaxf(o1.w, 0.f) * 0.f + fmaxf(o1.z, 0.f); o1.w = fmaxf(o1.w, 0.f);
        float4* outp = (float4*)(xnext + (size_t)node * HID + col_off);
        outp[sub] = o0;
        outp[sub + 8] = o1;
    }
}

// Fused global_add_pool + final linear: one block per graph (batch is sorted).
__global__ __launch_bounds__(128) void pool_final(
    const float* __restrict__ x, const int* __restrict__ batch,
    const float* __restrict__ fw, const float* __restrict__ fb,
    float* __restrict__ y) {
    int b = blockIdx.x;
    int t = threadIdx.x;
    __shared__ int sbeg, send;
    if (t == 0) {
        int lo = 0, hi = N_NODES;
        while (lo < hi) { int mid = (lo + hi) >> 1; if (batch[mid] < b) lo = mid + 1; else hi = mid; }
        sbeg = lo;
        hi = N_NODES;
        while (lo < hi) { int mid = (lo + hi) >> 1; if (batch[mid] < b + 1) lo = mid + 1; else hi = mid; }
        send = lo;
    }
    __syncthreads();
    float acc = 0.f;
    for (int n = sbeg; n < send; ++n) acc += x[(size_t)n * HID + t];
    __shared__ float sm[HID];
    sm[t] = acc * fw[t];
    __syncthreads();
    for (int off = 64; off > 0; off >>= 1) {
        if (t < off) sm[t] += sm[t + off];
        __syncthreads();
    }
    if (t == 0) y[b] = sm[0] + fb[0];
}

extern "C" void kernel_launch(void* const* d_in, const int* in_sizes, int n_in,
                              void* d_out, int out_size, void* d_ws, size_t ws_size,
                              hipStream_t stream) {
    const float* x_in    = (const float*)d_in[0];
    const int*   ei      = (const int*)d_in[1];
    const int*   di      = (const int*)d_in[2];
    const int*   batch   = (const int*)d_in[3];
    const float* lin_w   = (const float*)d_in[4];
    const float* att_src = (const float*)d_in[5];
    const float* att_dst = (const float*)d_in[6];
    const float* bias    = (const float*)d_in[7];
    const float* fw      = (const float*)d_in[8];
    const float* fb      = (const float*)d_in[9];
    float* y = (float*)d_out;

    char* wsb = (char*)d_ws;
    size_t off = 0;
    auto alloc_b = [&](size_t bytes) { void* p = (void*)(wsb + off);
                                       off += (bytes + 15) & ~(size_t)15; return p; };

    float* xbuf0 = (float*)alloc_b((size_t)N_NODES * HID * 4);
    float* xbuf1 = (float*)alloc_b((size_t)N_NODES * HID * 4);  // mat/pairs in build
    float* h     = (float*)alloc_b((size_t)N_NODES * OUT_D * 4);
    float* s_src = (float*)alloc_b(N_NODES * 4);
    float* s_dst = (float*)alloc_b(N_NODES * 4);
    int* matx  = (int*)alloc_b(((size_t)MATN2 + 1) * 4);
    int* bsum  = (int*)alloc_b(2048 * 4);
    int* bsumx = (int*)alloc_b(2048 * 4);
    int* rowS  = (int*)alloc_b((N_NODES + 1) * 4);
    int* rowD  = (int*)alloc_b((N_NODES + 1) * 4);
    u16* csrcS = (u16*)alloc_b((size_t)E_SPARSE * 2);
    u16* csrcD = (u16*)alloc_b((size_t)E_DENSE * 2);
    int* mat   = (int*)xbuf1;   // 10.4 MB <= 25.6 MB, dead after scan
    u32* pairs = (u32*)xbuf1;   // 16 MB   <= 25.6 MB, dead after bucket_to_csr

    const int* srcD = di;
    const int* dstD = di + E_DENSE;
    const int* srcS = ei;
    const int* dstS = ei + E_SPARSE;

    const int SCAN_BLKS = (MATN2 + 2047) / 2048;  // 1271

    // ---- two-level-key edge sort + slice-stable CSR (shared by layers) ----
    tile_count_all<<<NTD2 + NTS2, 256, 0, stream>>>(srcD, dstD, srcS, dstS, mat);
    scan_lvl0<<<SCAN_BLKS, 512, 0, stream>>>(mat, MATN2, matx, bsum);
    scan_lvl1b<<<1, 512, 0, stream>>>(bsum, SCAN_BLKS, bsumx);
    scan_add<<<(MATN2 + 256) / 256, 256, 0, stream>>>(matx, MATN2, bsumx,
                                                      E_DENSE + E_SPARSE);
    tile_scatter_all<<<NTD2 + NTS2, 256, 0, stream>>>(srcD, dstD, srcS, dstS,
                                                      matx, pairs);
    bucket_to_csr_all<<<2 * NBUCK, 256, 0, stream>>>(pairs, matx, rowD, csrcD,
                                                     rowS, csrcS);

    // layer 0 reads x_in directly; outputs ping-pong xbuf1 -> xbuf0 -> xbuf1
    const float* cur = x_in;
    float* bufs[3] = {xbuf1, xbuf0, xbuf1};
    const int ngrid = (N_NODES + 3) / 4;
    const int mm_grid = (N_NODES + NT - 1) / NT;
    for (int l = 0; l < N_LAYERS; ++l) {
        node_mm2<<<mm_grid, 256, 0, stream>>>(cur, lin_w + (size_t)l * HID * OUT_D,
                                              att_src + l * OUT_D, att_dst + l * OUT_D,
                                              h, s_src, s_dst);
        float* xn = bufs[l];
        gat_aggr2<<<2 * ngrid, 256, 0, stream>>>(rowS, csrcS, rowD, csrcD,
                                                 s_src, s_dst, h,
                                                 bias + l * OUT_D, xn, ngrid);
        cur = xn;
    }

    pool_final<<<N_GRAPHS, 128, 0, stream>>>(cur, batch, fw, fb, y);
}

// Round 13
// 652.924 us; speedup vs baseline: 8.8312x; 1.0585x over previous
//
#include <hip/hip_runtime.h>

#define N_NODES 50000
#define N_GRAPHS 500
#define E_SPARSE 800000
#define E_DENSE 3200000
#define IN_DIM 128
#define HID 128
#define OUT_D 64
#define N_LAYERS 3
#define NEG_SLOPE 0.2f

#define BUCKET_SHIFT 7                 // 128 nodes per bucket
#define BUCKET_N 128
#define NBUCK 391                      // ceil(50000/128)
#define NTD 1024                       // dense edge tiles
#define NTS 256                        // sparse edge tiles
#define TS_D 3125                      // E_DENSE / NTD
#define TS_S 3125                      // E_SPARSE / NTS
#define MD (NBUCK * NTD)               // dense matrix size = 400384
#define MATN (NBUCK * (NTD + NTS))     // 500480
#define NT 64                          // nodes per node_mm block
typedef unsigned int u32;
typedef unsigned short u16;

// ---------------- CSR construction (both branches in one pass) -------------
// PROVEN R8 build (absmax 0.0). Combined count matrix layout (bucket-major):
// dense (b,t) -> b*NTD + t ; sparse (b,t) -> MD + b*NTS + t.

__global__ __launch_bounds__(256) void tile_count_all(
    const int* __restrict__ dstD, const int* __restrict__ dstS,
    int* __restrict__ mat) {
    __shared__ int hc[NBUCK];
    int t = threadIdx.x;
    int tile = blockIdx.x;
    for (int i = t; i < NBUCK; i += 256) hc[i] = 0;
    __syncthreads();
    if (tile < NTD) {
        int beg = tile * TS_D, end = min(E_DENSE, beg + TS_D);
        for (int i = beg + t; i < end; i += 256)
            atomicAdd(&hc[dstD[i] >> BUCKET_SHIFT], 1);
        __syncthreads();
        for (int i = t; i < NBUCK; i += 256) mat[i * NTD + tile] = hc[i];
    } else {
        int st = tile - NTD;
        int beg = st * TS_S, end = min(E_SPARSE, beg + TS_S);
        for (int i = beg + t; i < end; i += 256)
            atomicAdd(&hc[dstS[i] >> BUCKET_SHIFT], 1);
        __syncthreads();
        for (int i = t; i < NBUCK; i += 256) mat[MD + i * NTS + st] = hc[i];
    }
}

// scan level-0: 512 threads, 4 elems/thread => 2048/block
__global__ void scan_lvl0(const int* __restrict__ cnt, int n,
                          int* __restrict__ out, int* __restrict__ bsum) {
    __shared__ int sm[512];
    int t = threadIdx.x;
    int base = blockIdx.x * 2048 + t * 4;
    int v0 = (base + 0 < n) ? cnt[base + 0] : 0;
    int v1 = (base + 1 < n) ? cnt[base + 1] : 0;
    int v2 = (base + 2 < n) ? cnt[base + 2] : 0;
    int v3 = (base + 3 < n) ? cnt[base + 3] : 0;
    int s = v0 + v1 + v2 + v3;
    sm[t] = s;
    __syncthreads();
    for (int off = 1; off < 512; off <<= 1) {
        int a = (t >= off) ? sm[t - off] : 0;
        __syncthreads();
        sm[t] += a;
        __syncthreads();
    }
    int excl = sm[t] - s;
    if (base + 0 < n) out[base + 0] = excl;
    if (base + 1 < n) out[base + 1] = excl + v0;
    if (base + 2 < n) out[base + 2] = excl + v0 + v1;
    if (base + 3 < n) out[base + 3] = excl + v0 + v1 + v2;
    if (t == 511) bsum[blockIdx.x] = sm[511];
}

// level-1: 256-thread LDS scan of block sums (nb <= 256)
__global__ void scan_lvl1(const int* __restrict__ bsum, int nb,
                          int* __restrict__ bsumx) {
    __shared__ int sm[256];
    int t = threadIdx.x;
    int v = (t < nb) ? bsum[t] : 0;
    sm[t] = v;
    __syncthreads();
    for (int off = 1; off < 256; off <<= 1) {
        int a = (t >= off) ? sm[t - off] : 0;
        __syncthreads();
        sm[t] += a;
        __syncthreads();
    }
    if (t < nb) bsumx[t] = sm[t] - v;
}

__global__ void scan_add(int* __restrict__ out, int n, const int* __restrict__ bsumx,
                         int Etot) {
    int i = blockIdx.x * blockDim.x + threadIdx.x;
    if (i < n) out[i] += bsumx[i >> 11];
    if (i == 0) out[n] = Etot;
}

// scatter packed (dst_low7<<16 | src) into globally-unique (bucket,tile) runs
__global__ __launch_bounds__(256) void tile_scatter_all(
    const int* __restrict__ srcD, const int* __restrict__ dstD,
    const int* __restrict__ srcS, const int* __restrict__ dstS,
    const int* __restrict__ matx, u32* __restrict__ pairs) {
    __shared__ int cur[NBUCK];
    int t = threadIdx.x;
    int tile = blockIdx.x;
    const int* src;
    const int* dst;
    int beg, end;
    if (tile < NTD) {
        for (int i = t; i < NBUCK; i += 256) cur[i] = matx[i * NTD + tile];
        src = srcD; dst = dstD;
        beg = tile * TS_D; end = min(E_DENSE, beg + TS_D);
    } else {
        int st = tile - NTD;
        for (int i = t; i < NBUCK; i += 256) cur[i] = matx[MD + i * NTS + st];
        src = srcS; dst = dstS;
        beg = st * TS_S; end = min(E_SPARSE, beg + TS_S);
    }
    __syncthreads();
    for (int i = beg + t; i < end; i += 256) {
        int d = dst[i];
        int pos = atomicAdd(&cur[d >> BUCKET_SHIFT], 1);
        pairs[pos] = (u32)src[i] | ((u32)(d & (BUCKET_N - 1)) << 16);
    }
}

// per-bucket local sort -> rowptr + u16 csrc. blocks [0,NBUCK)=dense, rest sparse.
__global__ __launch_bounds__(256) void bucket_to_csr_all(
    const u32* __restrict__ pairs, const int* __restrict__ matx,
    int* __restrict__ rowD, u16* __restrict__ csrcD,
    int* __restrict__ rowS, u16* __restrict__ csrcS) {
    int bid = blockIdx.x;
    int t = threadIdx.x;
    int b, beg, end, base;
    int* rowptr;
    u16* csrc;
    if (bid < NBUCK) {
        b = bid;
        beg = matx[b * NTD];
        end = matx[(b + 1) * NTD];     // b=390 -> matx[MD] = E_DENSE
        base = 0; rowptr = rowD; csrc = csrcD;
    } else {
        b = bid - NBUCK;
        beg = matx[MD + b * NTS];
        end = matx[MD + (b + 1) * NTS];  // last -> matx[MATN] = E_D+E_S
        base = E_DENSE; rowptr = rowS; csrc = csrcS;
    }
    __shared__ int lcnt[BUCKET_N];
    __shared__ int lofs[BUCKET_N];
    if (t < BUCKET_N) lcnt[t] = 0;
    __syncthreads();
    for (int k = beg + t; k < end; k += 256)
        atomicAdd(&lcnt[(pairs[k] >> 16) & (BUCKET_N - 1)], 1);
    __syncthreads();
    if (t < BUCKET_N) lofs[t] = lcnt[t];
    __syncthreads();
    for (int off = 1; off < BUCKET_N; off <<= 1) {
        int a = (t < BUCKET_N && t >= off) ? lofs[t - off] : 0;
        __syncthreads();
        if (t < BUCKET_N) lofs[t] += a;
        __syncthreads();
    }
    int node = (b << BUCKET_SHIFT) + t;
    int lbeg = beg - base;  // local CSR offset
    if (t < BUCKET_N) {
        int excl = lofs[t] - lcnt[t];
        if (node < N_NODES) rowptr[node] = lbeg + excl;
        lcnt[t] = excl;  // reuse as cursor
    }
    if (b == NBUCK - 1 && t == 0)
        rowptr[N_NODES] = (base == 0) ? E_DENSE : E_SPARSE;
    __syncthreads();
    for (int k = beg + t; k < end; k += 256) {
        u32 pr = pairs[k];
        int dl = (pr >> 16) & (BUCKET_N - 1);
        int pos = atomicAdd(&lcnt[dl], 1);
        csrc[lbeg + pos] = (u16)(pr & 0xffffu);
    }
}

// ---------------- per-layer kernels ----------------------------------------

// 256 threads, 64 nodes/block. W [k][16xfloat4] + X TRANSPOSED [k][64+pad]
// in LDS: both operands read as ds_read_b128; 4col x 4node register tile
// => 32B LDS / 16 FMA (node_mm2 was 36B/16FMA -> LDS-pipe-bound).
// Deterministic (no atomics), same k-order accumulation as node_mm2.
__global__ __launch_bounds__(256) void node_mm3(
    const float* __restrict__ x, const float* __restrict__ W,
    const float* __restrict__ a_s, const float* __restrict__ a_d,
    float* __restrict__ h, float* __restrict__ s_src, float* __restrict__ s_dst) {
    __shared__ float4 Wl4[IN_DIM * 16];     // [k][c4], 32 KB
    __shared__ float4 XT4[IN_DIM * 17];     // [k][ng(16)+1 pad], 34.8 KB
    int t = threadIdx.x;
    int nbase = blockIdx.x * NT;

    const float4* W4 = (const float4*)W;
#pragma unroll
    for (int i = 0; i < 8; ++i) Wl4[t + 256 * i] = W4[t + 256 * i];

    const float4* X4 = (const float4*)(x + (size_t)nbase * IN_DIM);
    float* XTf = (float*)XT4;
#pragma unroll
    for (int i = 0; i < 8; ++i) {
        int idx = t + 256 * i;          // 0..2047
        int nl = idx >> 5;              // local node 0..63
        int k4 = idx & 31;              // float4 index along k
        float4 v = make_float4(0.f, 0.f, 0.f, 0.f);
        if (nbase + nl < N_NODES) v = X4[idx];
        XTf[(k4 * 4 + 0) * 68 + nl] = v.x;
        XTf[(k4 * 4 + 1) * 68 + nl] = v.y;
        XTf[(k4 * 4 + 2) * 68 + nl] = v.z;
        XTf[(k4 * 4 + 3) * 68 + nl] = v.w;
    }
    __syncthreads();

    int cg = t & 15;   // 4-col group (cols cg*4..cg*4+3)
    int ng = t >> 4;   // 4-node group (nodes ng*4..ng*4+3)
    float4 A0 = make_float4(0.f, 0.f, 0.f, 0.f);
    float4 A1 = make_float4(0.f, 0.f, 0.f, 0.f);
    float4 A2 = make_float4(0.f, 0.f, 0.f, 0.f);
    float4 A3 = make_float4(0.f, 0.f, 0.f, 0.f);
#pragma unroll 4
    for (int k = 0; k < IN_DIM; ++k) {
        float4 w = Wl4[k * 16 + cg];
        float4 xv = XT4[k * 17 + ng];   // 4 nodes' x[k]
        A0.x += xv.x * w.x; A0.y += xv.x * w.y; A0.z += xv.x * w.z; A0.w += xv.x * w.w;
        A1.x += xv.y * w.x; A1.y += xv.y * w.y; A1.z += xv.y * w.z; A1.w += xv.y * w.w;
        A2.x += xv.z * w.x; A2.y += xv.z * w.y; A2.z += xv.z * w.z; A2.w += xv.z * w.w;
        A3.x += xv.w * w.x; A3.y += xv.w * w.y; A3.z += xv.w * w.z; A3.w += xv.w * w.w;
    }
    int n0 = nbase + ng * 4;
    float4* h4 = (float4*)h;
    if (n0 + 0 < N_NODES) h4[(size_t)(n0 + 0) * 16 + cg] = A0;
    if (n0 + 1 < N_NODES) h4[(size_t)(n0 + 1) * 16 + cg] = A1;
    if (n0 + 2 < N_NODES) h4[(size_t)(n0 + 2) * 16 + cg] = A2;
    if (n0 + 3 < N_NODES) h4[(size_t)(n0 + 3) * 16 + cg] = A3;

    float4 as4 = ((const float4*)a_s)[cg];
    float4 ad4 = ((const float4*)a_d)[cg];
    float ps0 = A0.x * as4.x + A0.y * as4.y + A0.z * as4.z + A0.w * as4.w;
    float ps1 = A1.x * as4.x + A1.y * as4.y + A1.z * as4.z + A1.w * as4.w;
    float ps2 = A2.x * as4.x + A2.y * as4.y + A2.z * as4.z + A2.w * as4.w;
    float ps3 = A3.x * as4.x + A3.y * as4.y + A3.z * as4.z + A3.w * as4.w;
    float pd0 = A0.x * ad4.x + A0.y * ad4.y + A0.z * ad4.z + A0.w * ad4.w;
    float pd1 = A1.x * ad4.x + A1.y * ad4.y + A1.z * ad4.z + A1.w * ad4.w;
    float pd2 = A2.x * ad4.x + A2.y * ad4.y + A2.z * ad4.z + A2.w * ad4.w;
    float pd3 = A3.x * ad4.x + A3.y * ad4.y + A3.z * ad4.z + A3.w * ad4.w;
#pragma unroll
    for (int off = 1; off < 16; off <<= 1) {
        ps0 += __shfl_xor(ps0, off); ps1 += __shfl_xor(ps1, off);
        ps2 += __shfl_xor(ps2, off); ps3 += __shfl_xor(ps3, off);
        pd0 += __shfl_xor(pd0, off); pd1 += __shfl_xor(pd1, off);
        pd2 += __shfl_xor(pd2, off); pd3 += __shfl_xor(pd3, off);
    }
    if (cg == 0) {
        if (n0 + 0 < N_NODES) { s_src[n0 + 0] = ps0; s_dst[n0 + 0] = pd0; }
        if (n0 + 1 < N_NODES) { s_src[n0 + 1] = ps1; s_dst[n0 + 1] = pd1; }
        if (n0 + 2 < N_NODES) { s_src[n0 + 2] = ps2; s_dst[n0 + 2] = pd2; }
        if (n0 + 3 < N_NODES) { s_src[n0 + 3] = ps3; s_dst[n0 + 3] = pd3; }
    }
}

// Fused GAT aggregation for both branches (proven R8 structure, 2x unroll).
__global__ __launch_bounds__(256) void gat_aggr2(
    const int* __restrict__ rowS, const u16* __restrict__ csrcS,
    const int* __restrict__ rowD, const u16* __restrict__ csrcD,
    const float* __restrict__ s_src, const float* __restrict__ s_dst,
    const float* __restrict__ h, const float* __restrict__ bias,
    float* __restrict__ xnext, int ngrid) {
    int bid = blockIdx.x;
    const int* rowptr;
    const u16* csrc;
    int col_off;
    if (bid < ngrid) { rowptr = rowS; csrc = csrcS; col_off = 0; }
    else { bid -= ngrid; rowptr = rowD; csrc = csrcD; col_off = OUT_D; }

    int node = bid * 4 + (threadIdx.x >> 6);
    if (node >= N_NODES) return;
    int lane = threadIdx.x & 63;
    int grp = lane >> 3;   // 0..7
    int sub = lane & 7;    // 0..7

    int beg = rowptr[node];
    int end = rowptr[node + 1];
    float sd = s_dst[node];

    const float4* h4 = (const float4*)h;
    float4 a0 = make_float4(0.f, 0.f, 0.f, 0.f);
    float4 a1 = make_float4(0.f, 0.f, 0.f, 0.f);
    float z = 0.f;

    int k = beg + grp;
    for (; k + 8 < end; k += 16) {
        int s0 = csrc[k];
        int s1 = csrc[k + 8];
        float e0 = s_src[s0] + sd;
        float e1 = s_src[s1] + sd;
        e0 = (e0 >= 0.f) ? e0 : NEG_SLOPE * e0;
        e1 = (e1 >= 0.f) ? e1 : NEG_SLOPE * e1;
        float p0 = __expf(e0);
        float p1 = __expf(e1);
        float4 u0 = h4[(size_t)s0 * 16 + sub];
        float4 u1 = h4[(size_t)s0 * 16 + sub + 8];
        float4 v0 = h4[(size_t)s1 * 16 + sub];
        float4 v1 = h4[(size_t)s1 * 16 + sub + 8];
        z += p0 + p1;
        a0.x += p0 * u0.x + p1 * v0.x; a0.y += p0 * u0.y + p1 * v0.y;
        a0.z += p0 * u0.z + p1 * v0.z; a0.w += p0 * u0.w + p1 * v0.w;
        a1.x += p0 * u1.x + p1 * v1.x; a1.y += p0 * u1.y + p1 * v1.y;
        a1.z += p0 * u1.z + p1 * v1.z; a1.w += p0 * u1.w + p1 * v1.w;
    }
    if (k < end) {
        int s0 = csrc[k];
        float e0 = s_src[s0] + sd;
        e0 = (e0 >= 0.f) ? e0 : NEG_SLOPE * e0;
        float p0 = __expf(e0);
        float4 u0 = h4[(size_t)s0 * 16 + sub];
        float4 u1 = h4[(size_t)s0 * 16 + sub + 8];
        z += p0;
        a0.x += p0 * u0.x; a0.y += p0 * u0.y; a0.z += p0 * u0.z; a0.w += p0 * u0.w;
        a1.x += p0 * u1.x; a1.y += p0 * u1.y; a1.z += p0 * u1.z; a1.w += p0 * u1.w;
    }
    if (grp == 0) {  // self-loop exactly once
        float e0 = s_src[node] + sd;
        e0 = (e0 >= 0.f) ? e0 : NEG_SLOPE * e0;
        float p0 = __expf(e0);
        float4 u0 = h4[(size_t)node * 16 + sub];
        float4 u1 = h4[(size_t)node * 16 + sub + 8];
        z += p0;
        a0.x += p0 * u0.x; a0.y += p0 * u0.y; a0.z += p0 * u0.z; a0.w += p0 * u0.w;
        a1.x += p0 * u1.x; a1.y += p0 * u1.y; a1.z += p0 * u1.z; a1.w += p0 * u1.w;
    }
#pragma unroll
    for (int off = 8; off <= 32; off <<= 1) {
        a0.x += __shfl_xor(a0.x, off); a0.y += __shfl_xor(a0.y, off);
        a0.z += __shfl_xor(a0.z, off); a0.w += __shfl_xor(a0.w, off);
        a1.x += __shfl_xor(a1.x, off); a1.y += __shfl_xor(a1.y, off);
        a1.z += __shfl_xor(a1.z, off); a1.w += __shfl_xor(a1.w, off);
        z += __shfl_xor(z, off);
    }
    if (grp == 0) {
        float inv = 1.f / z;
        const float4* b4 = (const float4*)bias;
        float4 b0 = b4[sub], b1 = b4[sub + 8];
        float4 o0, o1;
        o0.x = fmaxf(a0.x * inv + b0.x, 0.f); o0.y = fmaxf(a0.y * inv + b0.y, 0.f);
        o0.z = fmaxf(a0.z * inv + b0.z, 0.f); o0.w = fmaxf(a0.w * inv + b0.w, 0.f);
        o1.x = fmaxf(a1.x * inv + b1.x, 0.f); o1.y = fmaxf(a1.y * inv + b1.y, 0.f);
        o1.z = fmaxf(a1.z * inv + b1.z, 0.f); o1.w = fmaxf(a1.w * inv + b1.w, 0.f);
        float4* outp = (float4*)(xnext + (size_t)node * HID + col_off);
        outp[sub] = o0;
        outp[sub + 8] = o1;
    }
}

// Fused global_add_pool + final linear: one block per graph (batch is sorted).
__global__ __launch_bounds__(128) void pool_final(
    const float* __restrict__ x, const int* __restrict__ batch,
    const float* __restrict__ fw, const float* __restrict__ fb,
    float* __restrict__ y) {
    int b = blockIdx.x;
    int t = threadIdx.x;  // 0..127
    __shared__ int sbeg, send;
    if (t == 0) {
        int lo = 0, hi = N_NODES;
        while (lo < hi) { int mid = (lo + hi) >> 1; if (batch[mid] < b) lo = mid + 1; else hi = mid; }
        sbeg = lo;
        hi = N_NODES;
        while (lo < hi) { int mid = (lo + hi) >> 1; if (batch[mid] < b + 1) lo = mid + 1; else hi = mid; }
        send = lo;
    }
    __syncthreads();
    float acc = 0.f;
    for (int n = sbeg; n < send; ++n) acc += x[(size_t)n * HID + t];
    __shared__ float sm[HID];
    sm[t] = acc * fw[t];
    __syncthreads();
    for (int off = 64; off > 0; off >>= 1) {
        if (t < off) sm[t] += sm[t + off];
        __syncthreads();
    }
    if (t == 0) y[b] = sm[0] + fb[0];
}

extern "C" void kernel_launch(void* const* d_in, const int* in_sizes, int n_in,
                              void* d_out, int out_size, void* d_ws, size_t ws_size,
                              hipStream_t stream) {
    const float* x_in    = (const float*)d_in[0];
    const int*   ei      = (const int*)d_in[1];
    const int*   di      = (const int*)d_in[2];
    const int*   batch   = (const int*)d_in[3];
    const float* lin_w   = (const float*)d_in[4];
    const float* att_src = (const float*)d_in[5];
    const float* att_dst = (const float*)d_in[6];
    const float* bias    = (const float*)d_in[7];
    const float* fw      = (const float*)d_in[8];
    const float* fb      = (const float*)d_in[9];
    float* y = (float*)d_out;

    char* wsb = (char*)d_ws;
    size_t off = 0;
    auto alloc_b = [&](size_t bytes) { void* p = (void*)(wsb + off);
                                       off += (bytes + 15) & ~(size_t)15; return p; };

    float* xbuf0 = (float*)alloc_b((size_t)N_NODES * HID * 4);
    float* xbuf1 = (float*)alloc_b((size_t)N_NODES * HID * 4);  // pairs during build
    float* h     = (float*)alloc_b((size_t)N_NODES * OUT_D * 4);
    float* s_src = (float*)alloc_b(N_NODES * 4);
    float* s_dst = (float*)alloc_b(N_NODES * 4);
    int* mat     = (int*)alloc_b((size_t)MATN * 4);
    int* matx    = (int*)alloc_b(((size_t)MATN + 1) * 4);
    int* bsum    = (int*)alloc_b(256 * 4);
    int* bsumx   = (int*)alloc_b(256 * 4);
    int* rowS    = (int*)alloc_b((N_NODES + 1) * 4);
    int* rowD    = (int*)alloc_b((N_NODES + 1) * 4);
    u16* csrcS   = (u16*)alloc_b((size_t)E_SPARSE * 2);
    u16* csrcD   = (u16*)alloc_b((size_t)E_DENSE * 2);
    u32* pairs   = (u32*)xbuf1;  // 16 MB needed <= 25.6 MB available

    const int* srcD = di;
    const int* dstD = di + E_DENSE;
    const int* srcS = ei;
    const int* dstS = ei + E_SPARSE;

    const int SCAN_BLKS = (MATN + 2047) / 2048;  // 245 <= 256

    // ---- combined CSR build (proven R8, shared across layers) ----
    tile_count_all<<<NTD + NTS, 256, 0, stream>>>(dstD, dstS, mat);
    scan_lvl0<<<SCAN_BLKS, 512, 0, stream>>>(mat, MATN, matx, bsum);
    scan_lvl1<<<1, 256, 0, stream>>>(bsum, SCAN_BLKS, bsumx);
    scan_add<<<(MATN + 256) / 256, 256, 0, stream>>>(matx, MATN, bsumx,
                                                     E_DENSE + E_SPARSE);
    tile_scatter_all<<<NTD + NTS, 256, 0, stream>>>(srcD, dstD, srcS, dstS,
                                                    matx, pairs);
    bucket_to_csr_all<<<2 * NBUCK, 256, 0, stream>>>(pairs, matx, rowD, csrcD,
                                                     rowS, csrcS);

    // layer 0 reads x_in directly; outputs ping-pong xbuf1 -> xbuf0 -> xbuf1
    const float* cur = x_in;
    float* bufs[3] = {xbuf1, xbuf0, xbuf1};
    const int ngrid = (N_NODES + 3) / 4;
    const int mm_grid = (N_NODES + NT - 1) / NT;
    for (int l = 0; l < N_LAYERS; ++l) {
        node_mm3<<<mm_grid, 256, 0, stream>>>(cur, lin_w + (size_t)l * HID * OUT_D,
                                              att_src + l * OUT_D, att_dst + l * OUT_D,
                                              h, s_src, s_dst);
        float* xn = bufs[l];
        gat_aggr2<<<2 * ngrid, 256, 0, stream>>>(rowS, csrcS, rowD, csrcD,
                                                 s_src, s_dst, h,
                                                 bias + l * OUT_D, xn, ngrid);
        cur = xn;
    }

    pool_final<<<N_GRAPHS, 128, 0, stream>>>(cur, batch, fw, fb, y);
}